// Round 1
// baseline (1333.131 us; speedup 1.0000x reference)
//
#include <hip/hip_runtime.h>
#include <hip/hip_bf16.h>

#define D 128

// ---------------- CSR build ----------------

__global__ void hist_kernel(const int* __restrict__ dst, int* __restrict__ counts, int E) {
    for (int e = blockIdx.x * blockDim.x + threadIdx.x; e < E; e += gridDim.x * blockDim.x)
        atomicAdd(&counts[dst[e]], 1);
}

__global__ __launch_bounds__(256) void scan_block_sums(const int* __restrict__ counts,
                                                       int* __restrict__ bsums, int N) {
    __shared__ int sdata[256];
    int t = threadIdx.x;
    int idx = blockIdx.x * 256 + t;
    sdata[t] = (idx < N) ? counts[idx] : 0;
    __syncthreads();
    for (int s = 128; s > 0; s >>= 1) {
        if (t < s) sdata[t] += sdata[t + s];
        __syncthreads();
    }
    if (t == 0) bsums[blockIdx.x] = sdata[0];
}

// single block, 1024 threads; nb <= 1024
__global__ __launch_bounds__(1024) void scan_single(int* __restrict__ bsums, int nb,
                                                    int* __restrict__ offsets, int N, int E) {
    __shared__ int sdata[1024];
    int t = threadIdx.x;
    int v = (t < nb) ? bsums[t] : 0;
    sdata[t] = v;
    __syncthreads();
    for (int off = 1; off < 1024; off <<= 1) {
        int u = (t >= off) ? sdata[t - off] : 0;
        __syncthreads();
        sdata[t] += u;
        __syncthreads();
    }
    if (t < nb) bsums[t] = sdata[t] - v;  // exclusive prefix of block sums
    if (t == 0) offsets[N] = E;
}

__global__ __launch_bounds__(256) void scan_final(const int* __restrict__ counts,
                                                  const int* __restrict__ bprefix,
                                                  int* __restrict__ offsets, int N) {
    __shared__ int sdata[256];
    int t = threadIdx.x;
    int idx = blockIdx.x * 256 + t;
    int c = (idx < N) ? counts[idx] : 0;
    sdata[t] = c;
    __syncthreads();
    for (int off = 1; off < 256; off <<= 1) {
        int u = (t >= off) ? sdata[t - off] : 0;
        __syncthreads();
        sdata[t] += u;
        __syncthreads();
    }
    if (idx < N) offsets[idx] = bprefix[blockIdx.x] + (sdata[t] - c);
}

__global__ void copy_cursor(const int* __restrict__ offsets, int* __restrict__ cursor, int N) {
    for (int i = blockIdx.x * blockDim.x + threadIdx.x; i < N; i += gridDim.x * blockDim.x)
        cursor[i] = offsets[i];
}

__global__ void fill_csr(const int* __restrict__ src, const int* __restrict__ dst,
                         int* __restrict__ cursor, int* __restrict__ csr, int E) {
    for (int e = blockIdx.x * blockDim.x + threadIdx.x; e < E; e += gridDim.x * blockDim.x) {
        int d = dst[e];
        int p = atomicAdd(&cursor[d], 1);
        csr[p] = src[e];
    }
}

// ---------------- fused dual GEMM: m = x@W ; r = relu(x@Wr + br) ----------------

__global__ __launch_bounds__(256) void gemm_dual(const float* __restrict__ x,
                                                 const float* __restrict__ W,
                                                 const float* __restrict__ Wr,
                                                 const float* __restrict__ br,
                                                 float* __restrict__ m,
                                                 float* __restrict__ r, int N) {
    __shared__ float4 xs[32][32];  // 32 rows x 128 cols
    int t = threadIdx.x;
    int i0 = blockIdx.x * 32;
    const float4* xg = (const float4*)x;
    #pragma unroll
    for (int i = 0; i < 4; ++i) {
        int f = t + i * 256;  // 0..1023 float4 slots
        int row = f >> 5, col = f & 31;
        int gr = i0 + row;
        xs[row][col] = (gr < N) ? xg[gr * 32 + col] : make_float4(0.f, 0.f, 0.f, 0.f);
    }
    __syncthreads();

    int col = t & 127;
    int which = t >> 7;  // 0 -> m (W), 1 -> r (Wr)
    const float* Wsel = which ? Wr : W;

    float acc[32];
    #pragma unroll
    for (int rr = 0; rr < 32; ++rr) acc[rr] = 0.f;

    for (int k4 = 0; k4 < 32; ++k4) {
        int k = k4 * 4;
        float w0 = Wsel[(k + 0) * D + col];
        float w1 = Wsel[(k + 1) * D + col];
        float w2 = Wsel[(k + 2) * D + col];
        float w3 = Wsel[(k + 3) * D + col];
        #pragma unroll
        for (int rr = 0; rr < 32; ++rr) {
            float4 xv = xs[rr][k4];
            acc[rr] += xv.x * w0 + xv.y * w1 + xv.z * w2 + xv.w * w3;
        }
    }

    if (which == 0) {
        #pragma unroll
        for (int rr = 0; rr < 32; ++rr) {
            int gr = i0 + rr;
            if (gr < N) m[gr * D + col] = acc[rr];
        }
    } else {
        float bb = br[col];
        #pragma unroll
        for (int rr = 0; rr < 32; ++rr) {
            int gr = i0 + rr;
            if (gr < N) r[gr * D + col] = fmaxf(acc[rr] + bb, 0.f);
        }
    }
}

// ---------------- per-node gather + combine: out = relu(agg + b) + r ----------------

__global__ __launch_bounds__(256) void combine_kernel(const float* __restrict__ m,
                                                      const int* __restrict__ csr,
                                                      const int* __restrict__ offsets,
                                                      const float* __restrict__ bias,
                                                      const float* __restrict__ r,
                                                      float* __restrict__ out, int N) {
    int t = threadIdx.x;
    int node = blockIdx.x * 2 + (t >> 7);
    if (node >= N) return;
    int j = t & 127;
    int e0 = offsets[node], e1 = offsets[node + 1];
    float acc = 0.f;
    for (int e = e0; e < e1; ++e) {
        int s = csr[e];
        acc += m[s * D + j];
    }
    float v = fmaxf(acc + bias[j], 0.f) + r[node * D + j];
    out[node * D + j] = v;
}

// ---------------- BatchNorm ----------------

__global__ __launch_bounds__(256) void bn_stats(const float* __restrict__ buf,
                                                float* __restrict__ stats, int N) {
    int t = threadIdx.x;
    int j = t & 127, h = t >> 7;
    float s = 0.f, q = 0.f;
    for (int row = blockIdx.x * 2 + h; row < N; row += gridDim.x * 2) {
        float v = buf[row * D + j];
        s += v;
        q += v * v;
    }
    atomicAdd(&stats[j], s);
    atomicAdd(&stats[D + j], q);
}

__global__ void bn_finalize(float* __restrict__ stats, const float* __restrict__ g,
                            const float* __restrict__ be, float invN) {
    int j = threadIdx.x;
    float mu = stats[j] * invN;
    float var = stats[D + j] * invN - mu * mu;
    float sc = g[j] * rsqrtf(var + 1e-5f);
    stats[2 * D + j] = sc;
    stats[3 * D + j] = be[j] - mu * sc;
}

__global__ __launch_bounds__(256) void bn_apply(float* __restrict__ buf,
                                                const float* __restrict__ stats, int n4) {
    for (int i = blockIdx.x * blockDim.x + threadIdx.x; i < n4; i += gridDim.x * blockDim.x) {
        float4 v = ((const float4*)buf)[i];
        int c0 = (i * 4) & 127;
        float4 sc = *(const float4*)&stats[2 * D + c0];
        float4 sh = *(const float4*)&stats[3 * D + c0];
        v.x = v.x * sc.x + sh.x;
        v.y = v.y * sc.y + sh.y;
        v.z = v.z * sc.z + sh.z;
        v.w = v.w * sc.w + sh.w;
        ((float4*)buf)[i] = v;
    }
}

// ---------------- host ----------------

static inline char* align_up(char* p, size_t a) {
    return (char*)(((uintptr_t)p + (a - 1)) & ~(uintptr_t)(a - 1));
}

extern "C" void kernel_launch(void* const* d_in, const int* in_sizes, int n_in,
                              void* d_out, int out_size, void* d_ws, size_t ws_size,
                              hipStream_t stream) {
    const float* h   = (const float*)d_in[0];
    const int*   src = (const int*)d_in[1];
    const int*   dst = (const int*)d_in[2];
    const float* W0  = (const float*)d_in[3];
    const float* b0  = (const float*)d_in[4];
    const float* Wr0 = (const float*)d_in[5];
    const float* br0 = (const float*)d_in[6];
    const float* g0  = (const float*)d_in[7];
    const float* be0 = (const float*)d_in[8];
    const float* W1  = (const float*)d_in[9];
    const float* b1  = (const float*)d_in[10];
    const float* Wr1 = (const float*)d_in[11];
    const float* br1 = (const float*)d_in[12];
    const float* g1  = (const float*)d_in[13];
    const float* be1 = (const float*)d_in[14];

    const int N = in_sizes[0] / D;
    const int E = in_sizes[1];
    float* out = (float*)d_out;

    // workspace layout
    char* p = (char*)d_ws;
    float* m_buf  = (float*)p;                 p += (size_t)N * D * sizeof(float);
    float* x1_buf = (float*)p;                 p += (size_t)N * D * sizeof(float);
    p = align_up(p, 256);
    int* counts  = (int*)p;                    p += (size_t)N * sizeof(int);
    p = align_up(p, 256);
    int* offsets = (int*)p;                    p += (size_t)(N + 1) * sizeof(int);
    p = align_up(p, 256);
    int* cursor  = (int*)p;                    p += (size_t)N * sizeof(int);
    p = align_up(p, 256);
    int* bsums   = (int*)p;                    p += 1024 * sizeof(int);
    p = align_up(p, 256);
    int* csr     = (int*)p;                    p += (size_t)E * sizeof(int);
    p = align_up(p, 256);
    float* stats = (float*)p;                  p += 4 * D * sizeof(float);
    (void)ws_size;

    const int nb = (N + 255) / 256;
    const float invN = 1.0f / (float)N;

    // ---- CSR build (shared across both layers) ----
    hipMemsetAsync(counts, 0, (size_t)N * sizeof(int), stream);
    hist_kernel<<<2048, 256, 0, stream>>>(dst, counts, E);
    scan_block_sums<<<nb, 256, 0, stream>>>(counts, bsums, N);
    scan_single<<<1, 1024, 0, stream>>>(bsums, nb, offsets, N, E);
    scan_final<<<nb, 256, 0, stream>>>(counts, bsums, offsets, N);
    copy_cursor<<<512, 256, 0, stream>>>(offsets, cursor, N);
    fill_csr<<<2048, 256, 0, stream>>>(src, dst, cursor, csr, E);

    const int gemm_grid = (N + 31) / 32;
    const int comb_grid = (N + 1) / 2;
    const int n4 = N * D / 4;

    // ---- layer 1: input h -> x1_buf (r-branch staged in x1_buf, overwritten in place) ----
    gemm_dual<<<gemm_grid, 256, 0, stream>>>(h, W0, Wr0, br0, m_buf, x1_buf, N);
    combine_kernel<<<comb_grid, 256, 0, stream>>>(m_buf, csr, offsets, b0, x1_buf, x1_buf, N);
    hipMemsetAsync(stats, 0, 2 * D * sizeof(float), stream);
    bn_stats<<<256, 256, 0, stream>>>(x1_buf, stats, N);
    bn_finalize<<<1, D, 0, stream>>>(stats, g0, be0, invN);
    bn_apply<<<2048, 256, 0, stream>>>(x1_buf, stats, n4);

    // ---- layer 2: input x1_buf -> d_out (r-branch staged in d_out, overwritten in place) ----
    gemm_dual<<<gemm_grid, 256, 0, stream>>>(x1_buf, W1, Wr1, br1, m_buf, out, N);
    combine_kernel<<<comb_grid, 256, 0, stream>>>(m_buf, csr, offsets, b1, out, out, N);
    hipMemsetAsync(stats, 0, 2 * D * sizeof(float), stream);
    bn_stats<<<256, 256, 0, stream>>>(out, stats, N);
    bn_finalize<<<1, D, 0, stream>>>(stats, g1, be1, invN);
    bn_apply<<<2048, 256, 0, stream>>>(out, stats, n4);
}

// Round 2
// 979.695 us; speedup vs baseline: 1.3608x; 1.3608x over previous
//
#include <hip/hip_runtime.h>
#include <hip/hip_bf16.h>
#include <hip/hip_fp16.h>

#define D 128

// ---------------- CSR build ----------------

__global__ void hist_kernel(const int* __restrict__ dst, int* __restrict__ counts, int E) {
    for (int e = blockIdx.x * blockDim.x + threadIdx.x; e < E; e += gridDim.x * blockDim.x)
        atomicAdd(&counts[dst[e]], 1);
}

__global__ __launch_bounds__(256) void scan_block_sums(const int* __restrict__ counts,
                                                       int* __restrict__ bsums, int N) {
    __shared__ int sdata[256];
    int t = threadIdx.x;
    int idx = blockIdx.x * 256 + t;
    sdata[t] = (idx < N) ? counts[idx] : 0;
    __syncthreads();
    for (int s = 128; s > 0; s >>= 1) {
        if (t < s) sdata[t] += sdata[t + s];
        __syncthreads();
    }
    if (t == 0) bsums[blockIdx.x] = sdata[0];
}

// single block, 1024 threads; nb <= 1024
__global__ __launch_bounds__(1024) void scan_single(int* __restrict__ bsums, int nb,
                                                    int* __restrict__ offsets, int N, int E) {
    __shared__ int sdata[1024];
    int t = threadIdx.x;
    int v = (t < nb) ? bsums[t] : 0;
    sdata[t] = v;
    __syncthreads();
    for (int off = 1; off < 1024; off <<= 1) {
        int u = (t >= off) ? sdata[t - off] : 0;
        __syncthreads();
        sdata[t] += u;
        __syncthreads();
    }
    if (t < nb) bsums[t] = sdata[t] - v;  // exclusive prefix of block sums
    if (t == 0) offsets[N] = E;
}

__global__ __launch_bounds__(256) void scan_final(const int* __restrict__ counts,
                                                  const int* __restrict__ bprefix,
                                                  int* __restrict__ offsets, int N) {
    __shared__ int sdata[256];
    int t = threadIdx.x;
    int idx = blockIdx.x * 256 + t;
    int c = (idx < N) ? counts[idx] : 0;
    sdata[t] = c;
    __syncthreads();
    for (int off = 1; off < 256; off <<= 1) {
        int u = (t >= off) ? sdata[t - off] : 0;
        __syncthreads();
        sdata[t] += u;
        __syncthreads();
    }
    if (idx < N) offsets[idx] = bprefix[blockIdx.x] + (sdata[t] - c);
}

__global__ void copy_cursor(const int* __restrict__ offsets, int* __restrict__ cursor, int N) {
    for (int i = blockIdx.x * blockDim.x + threadIdx.x; i < N; i += gridDim.x * blockDim.x)
        cursor[i] = offsets[i];
}

__global__ void fill_csr(const int* __restrict__ src, const int* __restrict__ dst,
                         int* __restrict__ cursor, int* __restrict__ csr, int E) {
    for (int e = blockIdx.x * blockDim.x + threadIdx.x; e < E; e += gridDim.x * blockDim.x) {
        int d = dst[e];
        int p = atomicAdd(&cursor[d], 1);
        csr[p] = src[e];
    }
}

// ---------------- fused dual GEMM: m = (bn(x))@W ; r = relu((bn(x))@Wr + br) ----------------
// m stored as fp16; optional BN scale/shift applied to x on load.

__global__ __launch_bounds__(256) void gemm_dual(const float* __restrict__ x,
                                                 const float* __restrict__ W,
                                                 const float* __restrict__ Wr,
                                                 const float* __restrict__ br,
                                                 __half* __restrict__ m,
                                                 float* __restrict__ r,
                                                 const float* __restrict__ bn_sc,
                                                 const float* __restrict__ bn_sh,
                                                 int N) {
    __shared__ float4 xs[32][32];  // 32 rows x 128 cols
    int t = threadIdx.x;
    int i0 = blockIdx.x * 32;
    const float4* xg = (const float4*)x;
    #pragma unroll
    for (int i = 0; i < 4; ++i) {
        int f = t + i * 256;  // 0..1023 float4 slots
        int row = f >> 5, col = f & 31;
        int gr = i0 + row;
        float4 xv = (gr < N) ? xg[(size_t)gr * 32 + col] : make_float4(0.f, 0.f, 0.f, 0.f);
        if (bn_sc) {
            float4 sc = *(const float4*)&bn_sc[col * 4];
            float4 sh = *(const float4*)&bn_sh[col * 4];
            xv.x = xv.x * sc.x + sh.x;
            xv.y = xv.y * sc.y + sh.y;
            xv.z = xv.z * sc.z + sh.z;
            xv.w = xv.w * sc.w + sh.w;
        }
        xs[row][col] = xv;
    }
    __syncthreads();

    int col = t & 127;
    int which = t >> 7;  // 0 -> m (W), 1 -> r (Wr)
    const float* Wsel = which ? Wr : W;

    float acc[32];
    #pragma unroll
    for (int rr = 0; rr < 32; ++rr) acc[rr] = 0.f;

    for (int k4 = 0; k4 < 32; ++k4) {
        int k = k4 * 4;
        float w0 = Wsel[(k + 0) * D + col];
        float w1 = Wsel[(k + 1) * D + col];
        float w2 = Wsel[(k + 2) * D + col];
        float w3 = Wsel[(k + 3) * D + col];
        #pragma unroll
        for (int rr = 0; rr < 32; ++rr) {
            float4 xv = xs[rr][k4];
            acc[rr] += xv.x * w0 + xv.y * w1 + xv.z * w2 + xv.w * w3;
        }
    }

    if (which == 0) {
        #pragma unroll
        for (int rr = 0; rr < 32; ++rr) {
            int gr = i0 + rr;
            if (gr < N) m[(size_t)gr * D + col] = __float2half(acc[rr]);
        }
    } else {
        float bb = br[col];
        #pragma unroll
        for (int rr = 0; rr < 32; ++rr) {
            int gr = i0 + rr;
            if (gr < N) r[(size_t)gr * D + col] = fmaxf(acc[rr] + bb, 0.f);
        }
    }
}

// ---------------- per-node gather + combine + fused BN stats ----------------
// out = relu(sum_in m[src] + b) + r ; stats: 8-way replicated col sums/sumsq

__global__ __launch_bounds__(256) void combine_kernel(const __half* __restrict__ m,
                                                      const int* __restrict__ csr,
                                                      const int* __restrict__ offsets,
                                                      const float* __restrict__ bias,
                                                      const float* __restrict__ r,
                                                      float* __restrict__ out,
                                                      float* __restrict__ stats, int N) {
    __shared__ float4 sred[4][64];
    int t = threadIdx.x;
    int wave = t >> 6, lane = t & 63;
    int node = blockIdx.x * 4 + wave;
    float v0 = 0.f, v1 = 0.f;
    if (node < N) {
        int e0 = offsets[node], e1 = offsets[node + 1];
        const uint* mp = (const uint*)m;  // 2 fp16 per dword; row = 64 dwords
        float a0 = 0.f, a1 = 0.f, c0 = 0.f, c1 = 0.f;
        int e = e0;
        for (; e + 2 <= e1; e += 2) {
            int s0 = csr[e], s1 = csr[e + 1];
            uint p0 = mp[(size_t)s0 * 64 + lane];
            uint p1 = mp[(size_t)s1 * 64 + lane];
            float2 f0 = __half22float2(*reinterpret_cast<__half2*>(&p0));
            float2 f1 = __half22float2(*reinterpret_cast<__half2*>(&p1));
            a0 += f0.x; a1 += f0.y;
            c0 += f1.x; c1 += f1.y;
        }
        if (e < e1) {
            int s0 = csr[e];
            uint p0 = mp[(size_t)s0 * 64 + lane];
            float2 f0 = __half22float2(*reinterpret_cast<__half2*>(&p0));
            a0 += f0.x; a1 += f0.y;
        }
        a0 += c0; a1 += c1;
        float2 rv = *(const float2*)&r[(size_t)node * D + 2 * lane];
        float2 bv = *(const float2*)&bias[2 * lane];
        v0 = fmaxf(a0 + bv.x, 0.f) + rv.x;
        v1 = fmaxf(a1 + bv.y, 0.f) + rv.y;
        *(float2*)&out[(size_t)node * D + 2 * lane] = make_float2(v0, v1);
    }
    sred[wave][lane] = make_float4(v0, v1, v0 * v0, v1 * v1);
    __syncthreads();
    if (wave == 0) {
        float4 s0 = sred[0][lane], s1 = sred[1][lane], s2 = sred[2][lane], s3 = sred[3][lane];
        int copy = blockIdx.x & 7;
        float* ss = &stats[copy * 128];
        float* sq = &stats[1024 + copy * 128];
        atomicAdd(&ss[2 * lane],     s0.x + s1.x + s2.x + s3.x);
        atomicAdd(&ss[2 * lane + 1], s0.y + s1.y + s2.y + s3.y);
        atomicAdd(&sq[2 * lane],     s0.z + s1.z + s2.z + s3.z);
        atomicAdd(&sq[2 * lane + 1], s0.w + s1.w + s2.w + s3.w);
    }
}

// ---------------- BatchNorm finalize / apply ----------------

__global__ void bn_finalize(float* __restrict__ stats, const float* __restrict__ g,
                            const float* __restrict__ be, float invN) {
    int j = threadIdx.x;  // 128
    float s = 0.f, q = 0.f;
    #pragma unroll
    for (int c = 0; c < 8; ++c) {
        s += stats[c * 128 + j];
        q += stats[1024 + c * 128 + j];
    }
    float mu = s * invN;
    float var = q * invN - mu * mu;
    float sc = g[j] * rsqrtf(var + 1e-5f);
    stats[2048 + j] = sc;
    stats[2048 + 128 + j] = be[j] - mu * sc;
}

__global__ __launch_bounds__(256) void bn_apply(float* __restrict__ buf,
                                                const float* __restrict__ stats, int n4) {
    for (int i = blockIdx.x * blockDim.x + threadIdx.x; i < n4; i += gridDim.x * blockDim.x) {
        float4 v = ((const float4*)buf)[i];
        int c0 = (i * 4) & 127;
        float4 sc = *(const float4*)&stats[2048 + c0];
        float4 sh = *(const float4*)&stats[2048 + 128 + c0];
        v.x = v.x * sc.x + sh.x;
        v.y = v.y * sc.y + sh.y;
        v.z = v.z * sc.z + sh.z;
        v.w = v.w * sc.w + sh.w;
        ((float4*)buf)[i] = v;
    }
}

// ---------------- host ----------------

static inline char* align_up(char* p, size_t a) {
    return (char*)(((uintptr_t)p + (a - 1)) & ~(uintptr_t)(a - 1));
}

extern "C" void kernel_launch(void* const* d_in, const int* in_sizes, int n_in,
                              void* d_out, int out_size, void* d_ws, size_t ws_size,
                              hipStream_t stream) {
    const float* h   = (const float*)d_in[0];
    const int*   src = (const int*)d_in[1];
    const int*   dst = (const int*)d_in[2];
    const float* W0  = (const float*)d_in[3];
    const float* b0  = (const float*)d_in[4];
    const float* Wr0 = (const float*)d_in[5];
    const float* br0 = (const float*)d_in[6];
    const float* g0  = (const float*)d_in[7];
    const float* be0 = (const float*)d_in[8];
    const float* W1  = (const float*)d_in[9];
    const float* b1  = (const float*)d_in[10];
    const float* Wr1 = (const float*)d_in[11];
    const float* br1 = (const float*)d_in[12];
    const float* g1  = (const float*)d_in[13];
    const float* be1 = (const float*)d_in[14];

    const int N = in_sizes[0] / D;
    const int E = in_sizes[1];
    float* out = (float*)d_out;

    // workspace layout
    char* p = (char*)d_ws;
    __half* m_buf = (__half*)p;               p += (size_t)N * D * sizeof(__half);
    p = align_up(p, 256);
    float* x1_buf = (float*)p;                p += (size_t)N * D * sizeof(float);
    p = align_up(p, 256);
    int* counts  = (int*)p;                   p += (size_t)N * sizeof(int);
    p = align_up(p, 256);
    int* offsets = (int*)p;                   p += (size_t)(N + 1) * sizeof(int);
    p = align_up(p, 256);
    int* cursor  = (int*)p;                   p += (size_t)N * sizeof(int);
    p = align_up(p, 256);
    int* bsums   = (int*)p;                   p += 1024 * sizeof(int);
    p = align_up(p, 256);
    int* csr     = (int*)p;                   p += (size_t)E * sizeof(int);
    p = align_up(p, 256);
    float* stats1 = (float*)p;                p += 2304 * sizeof(float);
    p = align_up(p, 256);
    float* stats2 = (float*)p;                p += 2304 * sizeof(float);
    (void)ws_size;

    const int nb = (N + 255) / 256;
    const float invN = 1.0f / (float)N;

    // ---- CSR build (shared across both layers) ----
    hipMemsetAsync(counts, 0, (size_t)N * sizeof(int), stream);
    hist_kernel<<<2048, 256, 0, stream>>>(dst, counts, E);
    scan_block_sums<<<nb, 256, 0, stream>>>(counts, bsums, N);
    scan_single<<<1, 1024, 0, stream>>>(bsums, nb, offsets, N, E);
    scan_final<<<nb, 256, 0, stream>>>(counts, bsums, offsets, N);
    copy_cursor<<<512, 256, 0, stream>>>(offsets, cursor, N);
    fill_csr<<<2048, 256, 0, stream>>>(src, dst, cursor, csr, E);

    const int gemm_grid = (N + 31) / 32;
    const int comb_grid = (N + 3) / 4;
    const int n4 = N * D / 4;

    // ---- layer 1: h -> x1_buf (raw, pre-BN; BN folded into layer-2 gemm load) ----
    gemm_dual<<<gemm_grid, 256, 0, stream>>>(h, W0, Wr0, br0, m_buf, x1_buf,
                                             nullptr, nullptr, N);
    hipMemsetAsync(stats1, 0, 2048 * sizeof(float), stream);
    combine_kernel<<<comb_grid, 256, 0, stream>>>(m_buf, csr, offsets, b0, x1_buf,
                                                  x1_buf, stats1, N);
    bn_finalize<<<1, D, 0, stream>>>(stats1, g0, be0, invN);

    // ---- layer 2: bn(x1_buf) -> out ----
    gemm_dual<<<gemm_grid, 256, 0, stream>>>(x1_buf, W1, Wr1, br1, m_buf, out,
                                             stats1 + 2048, stats1 + 2048 + 128, N);
    hipMemsetAsync(stats2, 0, 2048 * sizeof(float), stream);
    combine_kernel<<<comb_grid, 256, 0, stream>>>(m_buf, csr, offsets, b1, out,
                                                  out, stats2, N);
    bn_finalize<<<1, D, 0, stream>>>(stats2, g1, be1, invN);
    bn_apply<<<2048, 256, 0, stream>>>(out, stats2, n4);
}